// Round 3
// baseline (706.301 us; speedup 1.0000x reference)
//
#include <hip/hip_runtime.h>
#include <stdint.h>

#define N_NODES 200000
#define NPL     12500
#define NLVL    16
#define DEG     8
#define EPL     (NPL*DEG)     // 100000
#define HD      128
#define KTOT    256           // concat K: [x | m]
#define NCOL    512           // padded output cols: [r|z|gxn|ghn]
#define MT      64            // rows per block
#define NBLK    196           // ceil(12500/64)
#define ASTR    264           // A-tile row stride (bf16), +8 pad -> 2-way banks (free)
#define BSTR    72            // Bt row stride (bf16), 64+8 pad -> 2-way banks (free)

typedef unsigned short u16;
typedef unsigned int   u32;

typedef __attribute__((ext_vector_type(8)))  short  short8;   // 8 bf16 = 4 VGPR (MFMA A/B frag)
typedef __attribute__((ext_vector_type(16))) float  f32x16;   // 32x32 MFMA C/D frag

__device__ __forceinline__ float bf2f(u32 u) { return __uint_as_float(u << 16); }
__device__ __forceinline__ float bflo(u32 u) { return __uint_as_float(u << 16); }
__device__ __forceinline__ float bfhi(u32 u) { return __uint_as_float(u & 0xFFFF0000u); }
__device__ __forceinline__ u16 f2bf(float f) {
  u32 u = __float_as_uint(f);
  return (u16)((u + 0x7FFFu + ((u >> 16) & 1u)) >> 16);   // RNE
}
__device__ __forceinline__ u32 pack2(float a, float b) {
  u32 ua = __float_as_uint(a), ub = __float_as_uint(b);
  ua = (ua + 0x7FFFu + ((ua >> 16) & 1u)) >> 16;
  ub = ((ub + 0x7FFFu + ((ub >> 16) & 1u)) >> 16) << 16;
  return ua | ub;
}
__device__ __forceinline__ float fsig(float x) {
  return __builtin_amdgcn_rcpf(1.f + __builtin_amdgcn_exp2f(-1.4426950408889634f * x));
}
__device__ __forceinline__ float ftanh(float x) {
  float t = __builtin_amdgcn_exp2f(2.8853900817779268f * x);   // e^(2x)
  return 1.f - 2.f * __builtin_amdgcn_rcpf(t + 1.f);           // inf-safe at both ends
}

// x init: x[index_map[i]] = bf16(features[i])  (index_map is a permutation: arange)
__global__ __launch_bounds__(256) void scatter_x(const float* __restrict__ f,
    const int* __restrict__ idx, u16* __restrict__ xb)
{
  const int t = blockIdx.x * 256 + threadIdx.x;   // 3.2M threads, 16 per row
  const int i = t >> 4, sg = (t & 15) * 8;
  const int d = idx[i];
  const float4 a = *(const float4*)(f + (size_t)i * HD + sg);
  const float4 b = *(const float4*)(f + (size_t)i * HD + sg + 4);
  uint4 o;
  o.x = pack2(a.x, a.y); o.y = pack2(a.z, a.w);
  o.z = pack2(b.x, b.y); o.w = pack2(b.z, b.w);
  *(uint4*)(xb + (size_t)d * HD + sg) = o;
}

// out[i] = fp32(h_final[index_map[i]])   (bf16 h -> float32 output)
__global__ __launch_bounds__(256) void gather_out(const u16* __restrict__ hb,
    const int* __restrict__ idx, float* __restrict__ o)
{
  const int t = blockIdx.x * 256 + threadIdx.x;
  const int i = t >> 4, sg = (t & 15) * 8;
  const int s = idx[i];
  const uint4 v = *(const uint4*)(hb + (size_t)s * HD + sg);
  float4 lo, hi;
  lo.x = bflo(v.x); lo.y = bfhi(v.x); lo.z = bflo(v.y); lo.w = bfhi(v.y);
  hi.x = bflo(v.z); hi.y = bfhi(v.z); hi.z = bflo(v.w); hi.w = bfhi(v.w);
  *(float4*)(o + (size_t)i * HD + sg)     = lo;
  *(float4*)(o + (size_t)i * HD + sg + 4) = hi;
}

// Wt[layer][col][k] (bf16), col in [0,512), k in [0,256):
//   col<256   : k<128 ? Wx[k][col] : Wh[k-128][col]        (combined r,z cols)
//   col<384   : k<128 ? Wx[k][col] : 0                      (gx_n cols)
//   col<512   : k>=128 ? Wh[k-128][col-128] : 0             (gh_n cols)
__global__ __launch_bounds__(256) void build_wt(const float* __restrict__ wx,
    const float* __restrict__ wh, u16* __restrict__ wt)
{
  const int t = blockIdx.x * 256 + threadIdx.x;   // < 262144
  const int l = t >> 17;
  const int r = t & 131071;
  const int col = r >> 8, k = r & 255;
  float v = 0.f;
  if (col < 256) {
    v = (k < 128) ? wx[(size_t)(l * 128 + k) * 384 + col]
                  : wh[(size_t)l * 49152 + (size_t)(k - 128) * 384 + col];
  } else if (col < 384) {
    if (k < 128) v = wx[(size_t)(l * 128 + k) * 384 + col];
  } else {
    if (k >= 128) v = wh[(size_t)l * 49152 + (size_t)(k - 128) * 384 + (col - 128)];
  }
  wt[(size_t)l * 131072 + (size_t)col * 256 + k] = f2bf(v);
}

// One level step: A=[x_rows | mean-of-8 h_rows] (M=64,K=256) x Wt^T (512 cols),
// fused GRU gate epilogue, bf16 h store. bias stays fp32 (folded into acc init).
__global__ __launch_bounds__(256) void level_step(
    const u16* __restrict__ x, u16* __restrict__ h,
    const u16* __restrict__ Wt, const float* __restrict__ bias,
    const int* __restrict__ esrc, int lvl)
{
  __shared__ __align__(16) u16 sA[MT * ASTR];     // 33,792 B
  __shared__ __align__(16) u16 sB[NCOL * BSTR];   // 73,728 B

  const int tid = threadIdx.x;
  const int blk = blockIdx.x;

  // ---- stage A-tile: x part (k 0..127) and m part (k 128..255) ----
  {
    const int row = tid >> 2, c0 = (tid & 3) * 32;
    const int lrow = blk * MT + row;
    const bool valid = (lrow < NPL);
    uint4 z4; z4.x = z4.y = z4.z = z4.w = 0u;
    uint4* dx = (uint4*)(sA + row * ASTR + c0);
    if (valid) {
      const uint4* xr = (const uint4*)(x + (size_t)(lvl * NPL + lrow) * HD + c0);
      #pragma unroll
      for (int t = 0; t < 4; ++t) dx[t] = xr[t];
    } else {
      #pragma unroll
      for (int t = 0; t < 4; ++t) dx[t] = z4;
    }
    uint4* dm = (uint4*)(sA + row * ASTR + HD + c0);
    if (lvl > 0 && valid) {
      float acc[32];
      #pragma unroll
      for (int i = 0; i < 32; ++i) acc[i] = 0.f;
      const int eb = (lvl - 1) * EPL + lrow * DEG;
      #pragma unroll
      for (int e = 0; e < DEG; ++e) {
        const int src = esrc[eb + e];
        const uint4* hr = (const uint4*)(h + (size_t)src * HD + c0);
        #pragma unroll
        for (int t = 0; t < 4; ++t) {
          uint4 v = hr[t];
          acc[t*8+0] += bflo(v.x); acc[t*8+1] += bfhi(v.x);
          acc[t*8+2] += bflo(v.y); acc[t*8+3] += bfhi(v.y);
          acc[t*8+4] += bflo(v.z); acc[t*8+5] += bfhi(v.z);
          acc[t*8+6] += bflo(v.w); acc[t*8+7] += bfhi(v.w);
        }
      }
      #pragma unroll
      for (int t = 0; t < 4; ++t) {
        uint4 o;
        o.x = pack2(acc[t*8+0]*0.125f, acc[t*8+1]*0.125f);
        o.y = pack2(acc[t*8+2]*0.125f, acc[t*8+3]*0.125f);
        o.z = pack2(acc[t*8+4]*0.125f, acc[t*8+5]*0.125f);
        o.w = pack2(acc[t*8+6]*0.125f, acc[t*8+7]*0.125f);
        dm[t] = o;
      }
    } else {
      #pragma unroll
      for (int t = 0; t < 4; ++t) dm[t] = z4;   // level 0: m = 0
    }
  }
  __syncthreads();

  const int wv = tid >> 6, lane = tid & 63;
  const int l31 = lane & 31, lq = lane >> 5;

  // acc[row-frag][gate-group]; fp32 bias folded into init (gh_n group gets 0)
  f32x16 acc[2][4];
  {
    const float b0 = bias[      32 * wv + l31];
    const float b1 = bias[128 + 32 * wv + l31];
    const float b2 = bias[256 + 32 * wv + l31];
    #pragma unroll
    for (int r = 0; r < 16; ++r) {
      acc[0][0][r] = b0; acc[1][0][r] = b0;
      acc[0][1][r] = b1; acc[1][1][r] = b1;
      acc[0][2][r] = b2; acc[1][2][r] = b2;
      acc[0][3][r] = 0.f; acc[1][3][r] = 0.f;
    }
  }

  // ---- K loop: BK=64 chunks of Wt staged to LDS, 32x32x16 bf16 MFMA ----
  for (int kc = 0; kc < KTOT; kc += 64) {
    #pragma unroll
    for (int j = 0; j < 16; ++j) {
      const int v = tid + 256 * j;            // 0..4095: 512 cols x 8 vec
      const int col = v >> 3, kq = v & 7;
      *(uint4*)(sB + col * BSTR + kq * 8) =
          *(const uint4*)(Wt + (size_t)col * KTOT + kc + kq * 8);
    }
    __syncthreads();
    #pragma unroll
    for (int ks = 0; ks < 64; ks += 16) {
      const short8 a0 = *(const short8*)(sA + (l31     ) * ASTR + kc + ks + lq * 8);
      const short8 a1 = *(const short8*)(sA + (32 + l31) * ASTR + kc + ks + lq * 8);
      #pragma unroll
      for (int c = 0; c < 4; ++c) {
        const short8 bb = *(const short8*)(sB + (c * 128 + 32 * wv + l31) * BSTR + ks + lq * 8);
        acc[0][c] = __builtin_amdgcn_mfma_f32_32x32x16_bf16(a0, bb, acc[0][c], 0, 0, 0);
        acc[1][c] = __builtin_amdgcn_mfma_f32_32x32x16_bf16(a1, bb, acc[1][c], 0, 0, 0);
      }
    }
    __syncthreads();
  }

  // ---- epilogue: r,z,n gates in-register; m from A-tile; bf16 store ----
  const int jcol = 32 * wv + l31;
  #pragma unroll
  for (int rf = 0; rf < 2; ++rf) {
    #pragma unroll
    for (int r = 0; r < 16; ++r) {
      const int rowe = rf * 32 + (r & 3) + 8 * (r >> 2) + 4 * lq;  // C-layout row
      const int lrow = blk * MT + rowe;
      if (lrow < NPL) {
        const float gr  = acc[rf][0][r];
        const float gz  = acc[rf][1][r];
        const float gxn = acc[rf][2][r];
        const float ghn = acc[rf][3][r];
        const float mv  = bf2f(sA[rowe * ASTR + HD + jcol]);
        const float rg  = fsig(gr);
        const float zg  = fsig(gz);
        const float ng  = ftanh(gxn + rg * ghn);
        const float hv  = (1.f - zg) * ng + zg * mv;
        h[(size_t)(lvl * NPL + lrow) * HD + jcol] = f2bf(hv);
      }
    }
  }
}

extern "C" void kernel_launch(void* const* d_in, const int* in_sizes, int n_in,
                              void* d_out, int out_size, void* d_ws, size_t ws_size,
                              hipStream_t stream)
{
  (void)in_sizes; (void)n_in; (void)out_size; (void)ws_size;
  const float* feats = (const float*)d_in[0];
  const float* wx    = (const float*)d_in[1];
  const float* wh    = (const float*)d_in[2];
  const float* bias  = (const float*)d_in[3];
  const int*   esrc  = (const int*)d_in[4];
  const int*   imap  = (const int*)d_in[6];
  float* out = (float*)d_out;

  char* ws = (char*)d_ws;
  u16* bufA = (u16*)ws;                       // 51,200,000 B  (x / layer-1 h)
  u16* bufB = (u16*)(ws + 51200000);          // 51,200,000 B  (layer-0 h)
  u16* wt   = (u16*)(ws + 102400000);         // 524,288 B     (2 x 512x256 bf16)

  scatter_x<<<12500, 256, 0, stream>>>(feats, imap, bufA);
  build_wt<<<1024, 256, 0, stream>>>(wx, wh, wt);

  for (int layer = 0; layer < 2; ++layer) {
    const u16* xp  = layer ? bufB : bufA;
    u16*       hp  = layer ? bufA : bufB;
    const u16* wtl = wt + (size_t)layer * 131072;
    const float* bl = bias + (size_t)layer * 384;
    for (int lvl = 0; lvl < NLVL; ++lvl)
      level_step<<<NBLK, 256, 0, stream>>>(xp, hp, wtl, bl, esrc, lvl);
  }
  gather_out<<<12500, 256, 0, stream>>>(bufA, imap, out);
}

// Round 4
// 698.111 us; speedup vs baseline: 1.0117x; 1.0117x over previous
//
#include <hip/hip_runtime.h>
#include <stdint.h>

#define N_NODES 200000
#define NPL     12500
#define NLVL    16
#define DEG     8
#define EPL     (NPL*DEG)     // 100000
#define HD      128
#define KTOT    256           // concat K: [x | m]
#define MT      64            // rows per block
#define NBLK    196           // ceil(12500/64)
#define ASTR    264           // A-tile row stride (bf16), +8 pad -> 2-way banks (free)

typedef unsigned short u16;
typedef unsigned int   u32;

typedef __attribute__((ext_vector_type(8)))  short  short8;   // 8 bf16 = 4 VGPR (MFMA A/B frag)
typedef __attribute__((ext_vector_type(16))) float  f32x16;   // 32x32 MFMA C/D frag

__device__ __forceinline__ float bf2f(u32 u) { return __uint_as_float(u << 16); }
__device__ __forceinline__ float bflo(u32 u) { return __uint_as_float(u << 16); }
__device__ __forceinline__ float bfhi(u32 u) { return __uint_as_float(u & 0xFFFF0000u); }
__device__ __forceinline__ u16 f2bf(float f) {
  u32 u = __float_as_uint(f);
  return (u16)((u + 0x7FFFu + ((u >> 16) & 1u)) >> 16);   // RNE
}
__device__ __forceinline__ u32 pack2(float a, float b) {
  u32 ua = __float_as_uint(a), ub = __float_as_uint(b);
  ua = (ua + 0x7FFFu + ((ua >> 16) & 1u)) >> 16;
  ub = ((ub + 0x7FFFu + ((ub >> 16) & 1u)) >> 16) << 16;
  return ua | ub;
}
__device__ __forceinline__ float fsig(float x) {
  return __builtin_amdgcn_rcpf(1.f + __builtin_amdgcn_exp2f(-1.4426950408889634f * x));
}
__device__ __forceinline__ float ftanh(float x) {
  float t = __builtin_amdgcn_exp2f(2.8853900817779268f * x);   // e^(2x)
  return 1.f - 2.f * __builtin_amdgcn_rcpf(t + 1.f);           // inf-safe at both ends
}

// x init: x[index_map[i]] = bf16(features[i])
__global__ __launch_bounds__(256) void scatter_x(const float* __restrict__ f,
    const int* __restrict__ idx, u16* __restrict__ xb)
{
  const int t = blockIdx.x * 256 + threadIdx.x;   // 3.2M threads, 16 per row
  const int i = t >> 4, sg = (t & 15) * 8;
  const int d = idx[i];
  const float4 a = *(const float4*)(f + (size_t)i * HD + sg);
  const float4 b = *(const float4*)(f + (size_t)i * HD + sg + 4);
  uint4 o;
  o.x = pack2(a.x, a.y); o.y = pack2(a.z, a.w);
  o.z = pack2(b.x, b.y); o.w = pack2(b.z, b.w);
  *(uint4*)(xb + (size_t)d * HD + sg) = o;
}

// out[i] = fp32(h_final[index_map[i]])
__global__ __launch_bounds__(256) void gather_out(const u16* __restrict__ hb,
    const int* __restrict__ idx, float* __restrict__ o)
{
  const int t = blockIdx.x * 256 + threadIdx.x;
  const int i = t >> 4, sg = (t & 15) * 8;
  const int s = idx[i];
  const uint4 v = *(const uint4*)(hb + (size_t)s * HD + sg);
  float4 lo, hi;
  lo.x = bflo(v.x); lo.y = bfhi(v.x); lo.z = bflo(v.y); lo.w = bfhi(v.y);
  hi.x = bflo(v.z); hi.y = bfhi(v.z); hi.z = bflo(v.w); hi.w = bfhi(v.w);
  *(float4*)(o + (size_t)i * HD + sg)     = lo;
  *(float4*)(o + (size_t)i * HD + sg + 4) = hi;
}

// Wt[layer][col][k] (bf16), col in [0,512), k in [0,256):
//   col<256 : k<128 ? Wx[k][col] : Wh[k-128][col]   (combined r,z cols)
//   col<384 : k<128 ? Wx[k][col] : 0                 (gx_n cols)
//   col<512 : k>=128 ? Wh[k-128][col-128] : 0        (gh_n cols)
__global__ __launch_bounds__(256) void build_wt(const float* __restrict__ wx,
    const float* __restrict__ wh, u16* __restrict__ wt)
{
  const int t = blockIdx.x * 256 + threadIdx.x;   // < 262144
  const int l = t >> 17;
  const int r = t & 131071;
  const int col = r >> 8, k = r & 255;
  float v = 0.f;
  if (col < 256) {
    v = (k < 128) ? wx[(size_t)(l * 128 + k) * 384 + col]
                  : wh[(size_t)l * 49152 + (size_t)(k - 128) * 384 + col];
  } else if (col < 384) {
    if (k < 128) v = wx[(size_t)(l * 128 + k) * 384 + col];
  } else {
    if (k >= 128) v = wh[(size_t)l * 49152 + (size_t)(k - 128) * 384 + (col - 128)];
  }
  wt[(size_t)l * 131072 + (size_t)col * 256 + k] = f2bf(v);
}

// Stage s: blocks [0,NBLK) do layer-0 level s; blocks [NBLK,2*NBLK) do
// layer-1 level s-1. A=[x|mean-of-8 h] (M=64,K=256) x Wt (512 cols, direct
// global reads, L2-resident), fused GRU epilogue, bf16 h store.
__global__ __launch_bounds__(256, 2) void level_step(
    u16* __restrict__ bufA, u16* __restrict__ bufB,
    const u16* __restrict__ wt, const float* __restrict__ bias,
    const int* __restrict__ esrc, int stage)
{
  __shared__ __align__(16) u16 sA[MT * ASTR];     // 33,792 B

  int blk = blockIdx.x, layer, lvl;
  if (blk < NBLK) { layer = 0; lvl = stage; }
  else            { layer = 1; lvl = stage - 1; blk -= NBLK; }
  if (lvl < 0 || lvl >= NLVL) return;

  const u16*   x  = layer ? bufB : bufA;          // L0: scattered x; L1: h0
  u16*         h  = layer ? bufA : bufB;          // L0: h0; L1: h1 (final)
  const u16*   Wt = wt  + (size_t)layer * 131072;
  const float* bs = bias + (size_t)layer * 384;

  const int tid = threadIdx.x;

  // ---- stage A-tile: x part (k 0..127) and m part (k 128..255) ----
  {
    const int row = tid >> 2, c0 = (tid & 3) * 32;
    const int lrow = blk * MT + row;
    const bool valid = (lrow < NPL);
    uint4 z4; z4.x = z4.y = z4.z = z4.w = 0u;
    uint4* dx = (uint4*)(sA + row * ASTR + c0);
    if (valid) {
      const uint4* xr = (const uint4*)(x + (size_t)(lvl * NPL + lrow) * HD + c0);
      #pragma unroll
      for (int t = 0; t < 4; ++t) dx[t] = xr[t];
    } else {
      #pragma unroll
      for (int t = 0; t < 4; ++t) dx[t] = z4;
    }
    uint4* dm = (uint4*)(sA + row * ASTR + HD + c0);
    if (lvl > 0 && valid) {
      float acc[32];
      #pragma unroll
      for (int i = 0; i < 32; ++i) acc[i] = 0.f;
      const int eb = (lvl - 1) * EPL + lrow * DEG;
      #pragma unroll
      for (int e = 0; e < DEG; ++e) {
        const int src = esrc[eb + e];
        const uint4* hr = (const uint4*)(h + (size_t)src * HD + c0);
        #pragma unroll
        for (int t = 0; t < 4; ++t) {
          uint4 v = hr[t];
          acc[t*8+0] += bflo(v.x); acc[t*8+1] += bfhi(v.x);
          acc[t*8+2] += bflo(v.y); acc[t*8+3] += bfhi(v.y);
          acc[t*8+4] += bflo(v.z); acc[t*8+5] += bfhi(v.z);
          acc[t*8+6] += bflo(v.w); acc[t*8+7] += bfhi(v.w);
        }
      }
      #pragma unroll
      for (int t = 0; t < 4; ++t) {
        uint4 o;
        o.x = pack2(acc[t*8+0]*0.125f, acc[t*8+1]*0.125f);
        o.y = pack2(acc[t*8+2]*0.125f, acc[t*8+3]*0.125f);
        o.z = pack2(acc[t*8+4]*0.125f, acc[t*8+5]*0.125f);
        o.w = pack2(acc[t*8+6]*0.125f, acc[t*8+7]*0.125f);
        dm[t] = o;
      }
    } else {
      #pragma unroll
      for (int t = 0; t < 4; ++t) dm[t] = z4;   // level 0: m = 0
    }
  }
  __syncthreads();   // the only barrier: K-loop below is barrier-free

  const int wv = tid >> 6, lane = tid & 63;
  const int l31 = lane & 31, lq = lane >> 5;

  // acc[row-frag][gate-group]; fp32 bias folded into init (gh_n group gets 0)
  f32x16 acc[2][4];
  {
    const float b0 = bs[      32 * wv + l31];
    const float b1 = bs[128 + 32 * wv + l31];
    const float b2 = bs[256 + 32 * wv + l31];
    #pragma unroll
    for (int r = 0; r < 16; ++r) {
      acc[0][0][r] = b0; acc[1][0][r] = b0;
      acc[0][1][r] = b1; acc[1][1][r] = b1;
      acc[0][2][r] = b2; acc[1][2][r] = b2;
      acc[0][3][r] = 0.f; acc[1][3][r] = 0.f;
    }
  }

  // ---- K loop: A from LDS, B direct from global (L1/L2-resident 256 KB) ----
  const u16* wbase = Wt + (size_t)(32 * wv + l31) * KTOT + lq * 8;
  for (int kc = 0; kc < KTOT; kc += 64) {
    #pragma unroll
    for (int ks = 0; ks < 64; ks += 16) {
      const short8 a0 = *(const short8*)(sA + (l31     ) * ASTR + kc + ks + lq * 8);
      const short8 a1 = *(const short8*)(sA + (32 + l31) * ASTR + kc + ks + lq * 8);
      #pragma unroll
      for (int c = 0; c < 4; ++c) {
        const short8 bb = *(const short8*)(wbase + (size_t)(c * 128) * KTOT + kc + ks);
        acc[0][c] = __builtin_amdgcn_mfma_f32_32x32x16_bf16(a0, bb, acc[0][c], 0, 0, 0);
        acc[1][c] = __builtin_amdgcn_mfma_f32_32x32x16_bf16(a1, bb, acc[1][c], 0, 0, 0);
      }
    }
  }

  // ---- epilogue: r,z,n gates in-register; m from A-tile; bf16 store ----
  const int jcol = 32 * wv + l31;
  #pragma unroll
  for (int rf = 0; rf < 2; ++rf) {
    #pragma unroll
    for (int r = 0; r < 16; ++r) {
      const int rowe = rf * 32 + (r & 3) + 8 * (r >> 2) + 4 * lq;  // C-layout row
      const int lrow = blk * MT + rowe;
      if (lrow < NPL) {
        const float gr  = acc[rf][0][r];
        const float gz  = acc[rf][1][r];
        const float gxn = acc[rf][2][r];
        const float ghn = acc[rf][3][r];
        const float mv  = bf2f(sA[rowe * ASTR + HD + jcol]);
        const float rg  = fsig(gr);
        const float zg  = fsig(gz);
        const float ng  = ftanh(gxn + rg * ghn);
        const float hv  = (1.f - zg) * ng + zg * mv;
        h[(size_t)(lvl * NPL + lrow) * HD + jcol] = f2bf(hv);
      }
    }
  }
}

extern "C" void kernel_launch(void* const* d_in, const int* in_sizes, int n_in,
                              void* d_out, int out_size, void* d_ws, size_t ws_size,
                              hipStream_t stream)
{
  (void)in_sizes; (void)n_in; (void)out_size; (void)ws_size;
  const float* feats = (const float*)d_in[0];
  const float* wx    = (const float*)d_in[1];
  const float* wh    = (const float*)d_in[2];
  const float* bias  = (const float*)d_in[3];
  const int*   esrc  = (const int*)d_in[4];
  const int*   imap  = (const int*)d_in[6];
  float* out = (float*)d_out;

  char* ws = (char*)d_ws;
  u16* bufA = (u16*)ws;                       // 51,200,000 B  (x, then h1)
  u16* bufB = (u16*)(ws + 51200000);          // 51,200,000 B  (h0)
  u16* wt   = (u16*)(ws + 102400000);         // 524,288 B     (2 x 512x256 bf16)

  scatter_x<<<12500, 256, 0, stream>>>(feats, imap, bufA);
  build_wt<<<1024, 256, 0, stream>>>(wx, wh, wt);

  for (int stage = 0; stage <= NLVL; ++stage)
    level_step<<<2 * NBLK, 256, 0, stream>>>(bufA, bufB, wt, bias, esrc, stage);

  gather_out<<<12500, 256, 0, stream>>>(bufA, imap, out);
}